// Round 1
// baseline (649.201 us; speedup 1.0000x reference)
//
#include <hip/hip_runtime.h>
#include <hip/hip_fp16.h>
#include <hip/hip_cooperative_groups.h>

namespace cg = cooperative_groups;

// Problem constants
#define BB 16
#define NN 1024
#define MMp 1024
#define MAX_ITER 100

constexpr float EPS_F    = 0.1f;
constexpr float INV_EPS  = 10.0f;
constexpr float MU_P     = 0.0009765625f + 1e-8f;      // 1/1024 + 1e-8  (== nu)
constexpr float LOG_MU   = -6.9314615656526045f;       // log(MU_P), folds to nearest fp32
constexpr float THRESH_B = 1.6f;                        // THRESH(0.1) * B(16): compare sum-err directly

// ---------------------------------------------------------------------------
// K1: E = exp(-C/eps) in fp16; init u=v=0, wv=1, err=0, ctr=0.
// grid 16384 x 256 : 4 E-elements per thread.
__global__ __launch_bounds__(256) void prep_kernel(
    const float* __restrict__ C, __half* __restrict__ E,
    float* __restrict__ u, float* __restrict__ v, float* __restrict__ wv,
    float* __restrict__ err, int* __restrict__ ctr)
{
    size_t gid = (size_t)blockIdx.x * 256 + threadIdx.x;   // 0..4194303
    float4 c = ((const float4*)C)[gid];
    __half2* E2 = (__half2*)E;
    E2[2*gid]   = __floats2half2_rn(__expf(-INV_EPS*c.x), __expf(-INV_EPS*c.y));
    E2[2*gid+1] = __floats2half2_rn(__expf(-INV_EPS*c.z), __expf(-INV_EPS*c.w));
    if (gid < BB*NN) { u[gid] = 0.f; v[gid] = 0.f; wv[gid] = 1.f; }
    if (gid < MAX_ITER) err[gid] = 0.f;
    if (gid < MAX_ITER*BB) ctr[gid] = 0;
}

// ---------------------------------------------------------------------------
// K2: cooperative Sinkhorn loop. 256 blocks x 1024 threads (1 block/CU).
// Block (b=blk>>4, sub=blk&15) owns rows [sub*64, sub*64+64) of batch b.
__global__ __launch_bounds__(1024, 4) void sink_iter(
    const __half* __restrict__ E, float* __restrict__ u, float* __restrict__ v,
    float* __restrict__ wv, float* __restrict__ T,
    float* __restrict__ err, int* __restrict__ ctr)
{
    cg::grid_group grid = cg::this_grid();
    const int tid  = threadIdx.x;
    const int lane = tid & 63;
    const int wav  = tid >> 6;            // 0..15
    const int blk  = blockIdx.x;          // 0..255
    const int b    = blk >> 4;
    const int sub  = blk & 15;

    const __half* Eb = E + ((size_t)b << 20);
    float* ub  = u  + (b << 10);
    float* vb  = v  + (b << 10);
    float* wvb = wv + (b << 10);
    float* Tb  = T  + (b << 10);

    __shared__ float wu_lds[64];   // wu for this block's 64 rows
    __shared__ float werr[16];
    __shared__ int   amLast;
    __shared__ float errv_s;

    for (int it = 0; it < MAX_ITER; ++it) {
        // ---------------- phase 1: u-update (row logsumexp in linear domain) ---
        // lane fragment of wv: floats [16*lane, 16*lane+16)
        float wf[16];
        {
            const float4* wv4 = (const float4*)wvb;
            #pragma unroll
            for (int k = 0; k < 4; ++k) {
                float4 t4 = wv4[(lane << 2) + k];
                wf[4*k+0]=t4.x; wf[4*k+1]=t4.y; wf[4*k+2]=t4.z; wf[4*k+3]=t4.w;
            }
        }
        float derr = 0.f;
        #pragma unroll
        for (int r = 0; r < 4; ++r) {
            int row = (sub << 6) + (wav << 2) + r;
            const uint4* Ep = (const uint4*)(Eb + ((size_t)row << 10));
            union { uint4 q; __half2 h[4]; } a0, a1;
            a0.q = Ep[2*lane];
            a1.q = Ep[2*lane + 1];
            float s = 0.f;
            #pragma unroll
            for (int k = 0; k < 4; ++k) {
                float2 f = __half22float2(a0.h[k]);
                s = fmaf(f.x, wf[2*k],   s);
                s = fmaf(f.y, wf[2*k+1], s);
            }
            #pragma unroll
            for (int k = 0; k < 4; ++k) {
                float2 f = __half22float2(a1.h[k]);
                s = fmaf(f.x, wf[8+2*k],   s);
                s = fmaf(f.y, wf[8+2*k+1], s);
            }
            #pragma unroll
            for (int off = 32; off >= 1; off >>= 1) s += __shfl_xor(s, off);
            float un = EPS_F * (LOG_MU - __logf(s));
            derr += fabsf(un - ub[row]);          // read old u before store (lockstep)
            if (lane == 0) {
                ub[row] = un;
                wu_lds[row - (sub << 6)] = MU_P / s;   // exp(u/eps) == mu / S
            }
        }
        if (lane == 0) werr[wav] = derr;
        if (tid < 64) Tb[(sub << 6) + tid] = 0.f;      // zero our T chunk for phase 2
        __syncthreads();
        if (wav == 0) {
            float e = (lane < 16) ? werr[lane] : 0.f;
            #pragma unroll
            for (int off = 8; off >= 1; off >>= 1) e += __shfl_xor(e, off);
            if (lane == 0) atomicAdd(err + it, e);
        }
        grid.sync();

        // ---------------- phase 2: v-update (column sums via atomics) ----------
        float acc = 0.f;
        {
            const __half* Ec = Eb + (((size_t)(sub << 6)) << 10) + tid;  // col = tid
            #pragma unroll 8
            for (int i0 = 0; i0 < 64; ++i0)
                acc = fmaf(__half2float(Ec[(size_t)i0 << 10]), wu_lds[i0], acc);
        }
        atomicAdd(&Tb[tid], acc);
        __threadfence();
        __syncthreads();
        if (tid == 0) amLast = (atomicAdd(&ctr[(it << 4) + b], 1) == 15) ? 1 : 0;
        __syncthreads();
        if (amLast) {                    // last block of batch b finalizes v
            __threadfence();
            float t = atomicAdd(&Tb[tid], 0.0f);       // coherent read
            vb[tid]  = EPS_F * (LOG_MU - __logf(t));   // log_nu == log_mu
            wvb[tid] = MU_P / t;
        }
        grid.sync();

        // ---------------- break check (uniform across grid) --------------------
        if (tid == 0) errv_s = atomicAdd(err + it, 0.0f);  // coherent read
        __syncthreads();
        if (errv_s < THRESH_B) break;
    }
}

// ---------------------------------------------------------------------------
// K3: pi = exp((u_i + v_j - C_ij)/eps), copy C, per-block partial cost.
// grid 16384 x 256; block = row (b,i).
__global__ __launch_bounds__(256) void epilogue(
    const float* __restrict__ C, const float* __restrict__ u, const float* __restrict__ v,
    float* __restrict__ outPi, float* __restrict__ outC, float* __restrict__ part)
{
    int blk = blockIdx.x;
    int b = blk >> 10;
    int i = blk & 1023;
    size_t base = (size_t)blk << 10;
    const float4* C4 = (const float4*)(C + base);
    const float4* v4 = (const float4*)(v + ((size_t)b << 10));
    float4* P4 = (float4*)(outPi + base);
    float4* O4 = (float4*)(outC + base);
    float ui = u[(b << 10) + i];
    int t = threadIdx.x;
    float4 c = C4[t];
    float4 vv = v4[t];
    float4 p;
    p.x = __expf((ui + vv.x - c.x) * INV_EPS);
    p.y = __expf((ui + vv.y - c.y) * INV_EPS);
    p.z = __expf((ui + vv.z - c.z) * INV_EPS);
    p.w = __expf((ui + vv.w - c.w) * INV_EPS);
    P4[t] = p;
    O4[t] = c;
    float cp = p.x*c.x + p.y*c.y + p.z*c.z + p.w*c.w;
    #pragma unroll
    for (int off = 32; off >= 1; off >>= 1) cp += __shfl_xor(cp, off);
    __shared__ float ps[4];
    if ((t & 63) == 0) ps[t >> 6] = cp;
    __syncthreads();
    if (t == 0) part[blk] = ps[0] + ps[1] + ps[2] + ps[3];
}

// K4: reduce 1024 partials per batch -> cost[16] (plain store, no atomics).
__global__ __launch_bounds__(1024) void cost_reduce(
    const float* __restrict__ part, float* __restrict__ outCost)
{
    int b = blockIdx.x;
    int t = threadIdx.x;
    float s = part[(b << 10) + t];
    #pragma unroll
    for (int off = 32; off >= 1; off >>= 1) s += __shfl_xor(s, off);
    __shared__ float ps[16];
    if ((t & 63) == 0) ps[t >> 6] = s;
    __syncthreads();
    if (t < 64) {
        float e = (t < 16) ? ps[t] : 0.f;
        #pragma unroll
        for (int off = 8; off >= 1; off >>= 1) e += __shfl_xor(e, off);
        if (t == 0) outCost[b] = e;
    }
}

// ---------------------------------------------------------------------------
extern "C" void kernel_launch(void* const* d_in, const int* in_sizes, int n_in,
                              void* d_out, int out_size, void* d_ws, size_t ws_size,
                              hipStream_t stream)
{
    const float* C = (const float*)d_in[2];   // x,y unused (shapes only)
    float* out = (float*)d_out;

    // ws layout (needs ~34 MB):
    char* ws = (char*)d_ws;
    __half* E  = (__half*)ws;                       // 16*1024*1024 fp16 = 32 MB
    float* u   = (float*)(ws + (size_t)33554432);   // 16384
    float* v   = u  + 16384;
    float* wv  = v  + 16384;
    float* T   = wv + 16384;
    float* err = T  + 16384;                        // 128 floats (100 used)
    int*   ctr = (int*)(err + 128);                 // 1600 ints
    float* part = (float*)(ctr + 1600);             // 16384 floats

    prep_kernel<<<16384, 256, 0, stream>>>(C, E, u, v, wv, err, ctr);

    void* args[] = { (void*)&E, (void*)&u, (void*)&v, (void*)&wv,
                     (void*)&T, (void*)&err, (void*)&ctr };
    hipLaunchCooperativeKernel((void*)sink_iter, dim3(256), dim3(1024),
                               args, 0, stream);

    float* outPi = out + 16;
    float* outC  = out + 16 + (size_t)16777216;
    epilogue<<<16384, 256, 0, stream>>>(C, u, v, outPi, outC, part);
    cost_reduce<<<16, 1024, 0, stream>>>(part, out);
}